// Round 1
// baseline (1155.047 us; speedup 1.0000x reference)
//
#include <hip/hip_runtime.h>

// Problem constants (from reference): N=1e6 rows, D_IN=128, D_OUT=64, C=64.
#define C_CLASSES 64
#define D_IN 128
#define D_OUT 64

// --- Kernel 1: segment-sum of raw inputs + counts --------------------------
// protos = (seg_sum(X)@W + cnt*b)/max(cnt,1)  -- matmul commutes with segsum,
// so the heavy pass is a pure memory-bound reduction: 512 MB read once.
//
// One wave per row. Lane l loads float2 at cols {2l, 2l+1} (coalesced 512B/row).
// LDS accumulator [64][128] f32 (32KB) with native ds_add_f32 (unsafeAtomicAdd).
// Column swizzle: cols >=64 rotated +1 within the half so every LDS atomic op
// is exactly 2 lanes/bank (2-way aliasing is free on gfx950 — m136).
// block=512, 33KB LDS -> 4 blocks/CU -> 32 waves/CU occupancy.
__device__ __forceinline__ int swz(int c) {
    return (c < 64) ? c : (64 + ((c - 63) & 63));
}

__global__ __launch_bounds__(512) void seg_sum_kernel(
    const float* __restrict__ x, const int* __restrict__ labels,
    float* __restrict__ gsum, float* __restrict__ gcnt, int n)
{
    __shared__ float ls[C_CLASSES * D_IN];
    __shared__ float lcnt[C_CLASSES];

    for (int i = threadIdx.x; i < C_CLASSES * D_IN; i += blockDim.x) ls[i] = 0.0f;
    if (threadIdx.x < C_CLASSES) lcnt[threadIdx.x] = 0.0f;
    __syncthreads();

    const int lane   = threadIdx.x & 63;
    const int gwave  = (int)((blockIdx.x * blockDim.x + threadIdx.x) >> 6);
    const int nwaves = (int)((gridDim.x * blockDim.x) >> 6);

    // Loop-invariant per-lane swizzled LDS column targets.
    const int c0 = lane * 2;
    const int s0 = swz(c0);
    const int s1 = swz(c0 + 1);

    for (int row = gwave; row < n; row += nwaves) {
        const float2 v = *(const float2*)(x + (size_t)row * D_IN + c0);
        const int lab  = labels[row];          // wave-uniform
        const int base = lab << 7;
        unsafeAtomicAdd(&ls[base + s0], v.x);  // ds_add_f32, 2-way banks
        unsafeAtomicAdd(&ls[base + s1], v.y);
        if (lane == 0) unsafeAtomicAdd(&lcnt[lab], 1.0f);
    }
    __syncthreads();

    // Flush block partials to global accumulator (device-scope fp32 atomics).
    for (int g = threadIdx.x; g < C_CLASSES * D_IN; g += blockDim.x) {
        const int lab = g >> 7;
        const int c   = g & 127;
        unsafeAtomicAdd(&gsum[g], ls[(lab << 7) + swz(c)]);
    }
    if (threadIdx.x < C_CLASSES)
        unsafeAtomicAdd(&gcnt[threadIdx.x], lcnt[threadIdx.x]);
}

// --- Kernel 2: tiny GEMM + bias + normalize --------------------------------
// out[c][e] = (S[c]@W[:,e] + cnt[c]*b[e]) / max(cnt[c],1)
// 4096 threads: wave shares class c (S row via scalar loads), lane = e
// (coalesced W/out accesses).
__global__ __launch_bounds__(256) void proto_kernel(
    const float* __restrict__ gsum, const float* __restrict__ gcnt,
    const float* __restrict__ W, const float* __restrict__ b,
    float* __restrict__ out)
{
    const int t = (int)(blockIdx.x * blockDim.x + threadIdx.x);
    const int c = t >> 6;
    const int e = t & 63;

    const float* srow = gsum + (c << 7);
    float acc = 0.0f;
#pragma unroll
    for (int k = 0; k < D_IN; ++k)
        acc = fmaf(srow[k], W[k * D_OUT + e], acc);

    const float cnt = gcnt[c];
    out[(c << 6) + e] = (acc + cnt * b[e]) / fmaxf(cnt, 1.0f);
}

extern "C" void kernel_launch(void* const* d_in, const int* in_sizes, int n_in,
                              void* d_out, int out_size, void* d_ws, size_t ws_size,
                              hipStream_t stream)
{
    const float* x      = (const float*)d_in[0];
    const int*   labels = (const int*)d_in[1];
    const float* W      = (const float*)d_in[2];
    const float* b      = (const float*)d_in[3];
    float*       out    = (float*)d_out;

    float* gsum = (float*)d_ws;                 // [64*128]
    float* gcnt = gsum + C_CLASSES * D_IN;      // [64]
    const int n = in_sizes[0] / D_IN;           // 1,000,000

    // d_ws is re-poisoned to 0xAA before every launch — zero the accumulators.
    hipMemsetAsync(d_ws, 0, (C_CLASSES * D_IN + C_CLASSES) * sizeof(float), stream);

    // 1024 blocks x 512 thr: 4 blocks/CU (33KB LDS each), grid-stride over rows.
    seg_sum_kernel<<<1024, 512, 0, stream>>>(x, labels, gsum, gcnt, n);

    // 64*64 outputs, one thread each.
    proto_kernel<<<(C_CLASSES * D_OUT) / 256, 256, 0, stream>>>(gsum, gcnt, W, b, out);
}

// Round 2
// 736.829 us; speedup vs baseline: 1.5676x; 1.5676x over previous
//
#include <hip/hip_runtime.h>

// Problem constants: N=1e6 rows, D_IN=128, D_OUT=64, C=64.
#define C_CLASSES 64
#define D_IN 128
#define D_OUT 64

// protos = (seg_sum(X)@W + cnt*b)/max(cnt,1)  (matmul commutes with segsum).
// R2: seg_sum(X) = OneHot(labels)^T @ X  -> MFMA one-hot GEMM. No LDS atomics.

typedef __attribute__((ext_vector_type(8))) __bf16 bf16x8;
typedef __attribute__((ext_vector_type(8))) unsigned short us8;
typedef __attribute__((ext_vector_type(4))) float f32x4;

union frag_cast { us8 u; bf16x8 b; };

// float -> bf16 with round-to-nearest-even (inputs are finite N(0,1)).
__device__ __forceinline__ unsigned short f2bf(float f) {
    unsigned u = __float_as_uint(f);
    unsigned r = u + 0x7FFFu + ((u >> 16) & 1u);
    return (unsigned short)(r >> 16);
}

// --- Kernel 1: S = OneHot^T @ X via mfma_f32_16x16x32_bf16 -----------------
// Block = 256 thr = 4 waves. Block covers the FULL 64x128 output for a
// grid-strided set of 32-row K-chunks; wave w owns cols [32w, 32w+32)
// = 4 class-tiles (M) x 2 col-tiles (N) = 8 accum frags (32 AGPRs).
//
// Fragment layouts (m89/m120 verified):
//   A[m][k]: m = lane&15 (class-in-tile), k = (lane>>4)*8 + j
//   B[k][n]: k = (lane>>4)*8 + j,         n = lane&15 (col-in-tile)
//   D[m][n]: m = (lane>>4)*4 + r,         n = lane&15
__global__ __launch_bounds__(256) void seg_mm_kernel(
    const float* __restrict__ x, const int* __restrict__ labels,
    float* __restrict__ gsum, int n)
{
    const int lane  = threadIdx.x & 63;
    const int wave  = threadIdx.x >> 6;   // 0..3
    const int n16   = lane & 15;          // tile row/col index
    const int quad  = lane >> 4;          // 0..3
    const int cb    = wave * 32;          // this wave's column base

    f32x4 acc[4][2];
#pragma unroll
    for (int t = 0; t < 4; ++t)
#pragma unroll
        for (int u = 0; u < 2; ++u)
            acc[t][u] = (f32x4){0.f, 0.f, 0.f, 0.f};

    const int stride = (int)gridDim.x * 32;

    for (int rb = (int)blockIdx.x * 32; rb < n; rb += stride) {
        // labels for this lane's 8 K-slots: rows rb + quad*8 + j  (32B aligned)
        const int4 l0 = *(const int4*)(labels + rb + quad * 8);
        const int4 l1 = *(const int4*)(labels + rb + quad * 8 + 4);
        const int labv[8] = {l0.x, l0.y, l0.z, l0.w, l1.x, l1.y, l1.z, l1.w};

        // B frags: X[rb + quad*8 + j][cb + 16u + n16], loaded as f32 dwords.
        // Each wave-instr covers 4 x 64B segments; every 64B chunk of every
        // row is read exactly once across the block -> no overfetch.
        const float* xp = x + (size_t)(rb + quad * 8) * D_IN + cb + n16;
        float bflt[2][8];
#pragma unroll
        for (int j = 0; j < 8; ++j) {
            bflt[0][j] = xp[(size_t)j * D_IN];
            bflt[1][j] = xp[(size_t)j * D_IN + 16];
        }

        frag_cast bfrag[2];
#pragma unroll
        for (int u = 0; u < 2; ++u)
#pragma unroll
            for (int j = 0; j < 8; ++j)
                bfrag[u].u[j] = f2bf(bflt[u][j]);

        // A frags: one-hot built in registers. a[t][j] = (lab == 16t+n16)
        frag_cast afrag[4];
#pragma unroll
        for (int t = 0; t < 4; ++t)
#pragma unroll
            for (int j = 0; j < 8; ++j)
                afrag[t].u[j] = (labv[j] == t * 16 + n16) ? (unsigned short)0x3F80u
                                                          : (unsigned short)0u;

#pragma unroll
        for (int t = 0; t < 4; ++t)
#pragma unroll
            for (int u = 0; u < 2; ++u)
                acc[t][u] = __builtin_amdgcn_mfma_f32_16x16x32_bf16(
                    afrag[t].b, bfrag[u].b, acc[t][u], 0, 0, 0);
    }

    // Epilogue: D[class = 16t + quad*4 + r][col = cb + 16u + n16]
#pragma unroll
    for (int t = 0; t < 4; ++t)
#pragma unroll
        for (int u = 0; u < 2; ++u)
#pragma unroll
            for (int r = 0; r < 4; ++r)
                unsafeAtomicAdd(&gsum[(t * 16 + quad * 4 + r) * D_IN + cb + u * 16 + n16],
                                acc[t][u][r]);
}

// --- Kernel 2: class counts via wave ballot (no atomics in the hot loop) ---
__global__ __launch_bounds__(256) void count_kernel(
    const int* __restrict__ labels, float* __restrict__ gcnt, int n)
{
    const int lane = threadIdx.x & 63;
    const int gw   = (int)(blockIdx.x * blockDim.x + threadIdx.x) >> 6;
    const int nw   = (int)(gridDim.x * blockDim.x) >> 6;

    int cnt = 0;
    for (int base = gw * 64; base < n; base += nw * 64) {  // n % 64 == 0
        const int lab = labels[base + lane];
#pragma unroll
        for (int c = 0; c < C_CLASSES; ++c) {
            unsigned long long m = __ballot(lab == c);
            cnt += (lane == c) ? __popcll(m) : 0;
        }
    }
    unsafeAtomicAdd(&gcnt[lane], (float)cnt);  // lane == class
}

// --- Kernel 3: tiny GEMM + bias + normalize --------------------------------
__global__ __launch_bounds__(256) void proto_kernel(
    const float* __restrict__ gsum, const float* __restrict__ gcnt,
    const float* __restrict__ W, const float* __restrict__ b,
    float* __restrict__ out)
{
    const int t = (int)(blockIdx.x * blockDim.x + threadIdx.x);
    const int c = t >> 6;
    const int e = t & 63;

    const float* srow = gsum + (c << 7);
    float acc = 0.0f;
#pragma unroll
    for (int k = 0; k < D_IN; ++k)
        acc = fmaf(srow[k], W[k * D_OUT + e], acc);

    const float cnt = gcnt[c];
    out[(c << 6) + e] = (acc + cnt * b[e]) / fmaxf(cnt, 1.0f);
}

extern "C" void kernel_launch(void* const* d_in, const int* in_sizes, int n_in,
                              void* d_out, int out_size, void* d_ws, size_t ws_size,
                              hipStream_t stream)
{
    const float* x      = (const float*)d_in[0];
    const int*   labels = (const int*)d_in[1];
    const float* W      = (const float*)d_in[2];
    const float* b      = (const float*)d_in[3];
    float*       out    = (float*)d_out;

    float* gsum = (float*)d_ws;                 // [64*128]
    float* gcnt = gsum + C_CLASSES * D_IN;      // [64]
    const int n = in_sizes[0] / D_IN;           // 1,000,000 (multiple of 64)

    hipMemsetAsync(d_ws, 0, (C_CLASSES * D_IN + C_CLASSES) * sizeof(float), stream);

    // 1024 blocks x 4 waves: 4 blocks/CU, grid-stride over 32-row chunks.
    seg_mm_kernel<<<1024, 256, 0, stream>>>(x, labels, gsum, n);

    count_kernel<<<256, 256, 0, stream>>>(labels, gcnt, n);

    proto_kernel<<<(C_CLASSES * D_OUT) / 256, 256, 0, stream>>>(gsum, gcnt, W, b, out);
}

// Round 3
// 707.873 us; speedup vs baseline: 1.6317x; 1.0409x over previous
//
#include <hip/hip_runtime.h>

// Problem constants: N=1e6 rows, D_IN=128, D_OUT=64, C=64.
#define C_CLASSES 64
#define D_IN 128
#define D_OUT 64
#define CHUNK 32               // rows per K-chunk (one 16x16x32 K-step)
#define CHUNK_FLTS (CHUNK * D_IN)   // 4096 floats = 16 KB

// protos = (seg_sum(X)@W + cnt*b)/max(cnt,1); seg_sum(X) = OneHot(labels)^T @ X
// R3: m97-style LDS staging. B-frags can't be fed by vectorized global loads
// (per-lane elements stride along K = rows), so: global_load_lds dwordx4
// (linear, 1KB/wave-instr) -> double-buffered LDS -> ds_read_b32 fragments.

typedef __attribute__((ext_vector_type(8))) __bf16 bf16x8;
typedef __attribute__((ext_vector_type(8))) unsigned short us8;
typedef __attribute__((ext_vector_type(4))) float f32x4;

union frag_cast { us8 u; bf16x8 b; };

// float -> bf16 round-to-nearest-even.
__device__ __forceinline__ unsigned short f2bf(float f) {
    unsigned u = __float_as_uint(f);
    unsigned r = u + 0x7FFFu + ((u >> 16) & 1u);
    return (unsigned short)(r >> 16);
}

// Async global->LDS, 16B per lane. LDS dest = wave-uniform base + lane*16.
__device__ __forceinline__ void stage16(const float* g, float* l) {
    __builtin_amdgcn_global_load_lds(
        (const __attribute__((address_space(1))) unsigned int*)g,
        (__attribute__((address_space(3))) unsigned int*)l, 16, 0, 0);
}

// --- Kernel 1: S = OneHot^T @ X via mfma_f32_16x16x32_bf16, LDS-staged -----
// Block = 256 thr = 4 waves; block covers full 64x128 output. Wave w owns
// cols [32w,32w+32): 4 class-tiles x 2 col-tiles = 8 acc frags.
// Layouts (R2-verified): A[m][k] m=lane&15,k=quad*8+j; B[k][n] n=lane&15;
// D[m][n] m=quad*4+r, n=lane&15.
__global__ __launch_bounds__(256) void seg_mm_kernel(
    const float* __restrict__ x, const int* __restrict__ labels,
    float* __restrict__ gsum, int n)
{
    __shared__ float buf[2][CHUNK_FLTS];   // 2 x 16 KB double buffer

    const int lane = threadIdx.x & 63;
    const int wave = threadIdx.x >> 6;     // 0..3
    const int n16  = lane & 15;
    const int quad = lane >> 4;            // 0..3
    const int cb   = wave * 32;            // wave's column base

    f32x4 acc[4][2];
#pragma unroll
    for (int t = 0; t < 4; ++t)
#pragma unroll
        for (int u = 0; u < 2; ++u)
            acc[t][u] = (f32x4){0.f, 0.f, 0.f, 0.f};

    const int stride = (int)gridDim.x * CHUNK;
    const int rb0    = (int)blockIdx.x * CHUNK;
    // Per-wave stage slice: wave w moves floats [w*256*i? ...] — thread t
    // (t = w*64+lane) handles 16B at float offset r*1024 + w*256 + lane*4,
    // r = 0..3. Wave-uniform LDS base = r*1024 + w*256.
    const int lslice = wave * 256;         // float offset of this wave's slice
    const int gslice = lslice + lane * 4;  // per-lane float offset in chunk

    // Prefetch chunk 0 (DMA) + its labels (registers).
    if (rb0 < n) {
#pragma unroll
        for (int r = 0; r < 4; ++r)
            stage16(x + (size_t)rb0 * D_IN + r * 1024 + gslice,
                    &buf[0][r * 1024 + lslice]);
    }
    int4 pl0 = {0,0,0,0}, pl1 = {0,0,0,0};
    if (rb0 < n) {
        pl0 = *(const int4*)(labels + rb0 + quad * 8);
        pl1 = *(const int4*)(labels + rb0 + quad * 8 + 4);
    }

    int bufi = 0;
    for (int rb = rb0; rb < n; rb += stride, bufi ^= 1) {
        __syncthreads();   // drain stage(rb); prev chunk's reads complete

        const int rbn = rb + stride;
        const int labv[8] = {pl0.x, pl0.y, pl0.z, pl0.w,
                             pl1.x, pl1.y, pl1.z, pl1.w};
        if (rbn < n) {     // kick off next chunk's DMA + label prefetch
#pragma unroll
            for (int r = 0; r < 4; ++r)
                stage16(x + (size_t)rbn * D_IN + r * 1024 + gslice,
                        &buf[bufi ^ 1][r * 1024 + lslice]);
            pl0 = *(const int4*)(labels + rbn + quad * 8);
            pl1 = *(const int4*)(labels + rbn + quad * 8 + 4);
        }

        // B frags from LDS: buf[k*128 + cb + u*16 + n16], k = quad*8+j.
        const float* lb = &buf[bufi][(quad * 8) * D_IN + cb + n16];
        frag_cast bfrag[2];
#pragma unroll
        for (int u = 0; u < 2; ++u)
#pragma unroll
            for (int j = 0; j < 8; ++j)
                bfrag[u].u[j] = f2bf(lb[j * D_IN + u * 16]);

        // A frags: one-hot from prefetched labels.
        frag_cast afrag[4];
#pragma unroll
        for (int t = 0; t < 4; ++t)
#pragma unroll
            for (int j = 0; j < 8; ++j)
                afrag[t].u[j] = (labv[j] == t * 16 + n16)
                                    ? (unsigned short)0x3F80u : (unsigned short)0u;

#pragma unroll
        for (int t = 0; t < 4; ++t)
#pragma unroll
            for (int u = 0; u < 2; ++u)
                acc[t][u] = __builtin_amdgcn_mfma_f32_16x16x32_bf16(
                    afrag[t].b, bfrag[u].b, acc[t][u], 0, 0, 0);

        __syncthreads();   // all waves done reading buf[bufi] before overwrite
    }

    // Epilogue: D[class = 16t + quad*4 + r][col = cb + 16u + n16]
#pragma unroll
    for (int t = 0; t < 4; ++t)
#pragma unroll
        for (int u = 0; u < 2; ++u)
#pragma unroll
            for (int r = 0; r < 4; ++r)
                unsafeAtomicAdd(&gsum[(t * 16 + quad * 4 + r) * D_IN + cb + u * 16 + n16],
                                acc[t][u][r]);
}

// --- Kernel 2: class counts via wave ballot --------------------------------
__global__ __launch_bounds__(256) void count_kernel(
    const int* __restrict__ labels, float* __restrict__ gcnt, int n)
{
    const int lane = threadIdx.x & 63;
    const int gw   = (int)(blockIdx.x * blockDim.x + threadIdx.x) >> 6;
    const int nw   = (int)(gridDim.x * blockDim.x) >> 6;

    int cnt = 0;
    for (int base = gw * 64; base < n; base += nw * 64) {  // n % 64 == 0
        const int lab = labels[base + lane];
#pragma unroll
        for (int c = 0; c < C_CLASSES; ++c) {
            unsigned long long m = __ballot(lab == c);
            cnt += (lane == c) ? __popcll(m) : 0;
        }
    }
    unsafeAtomicAdd(&gcnt[lane], (float)cnt);  // lane == class
}

// --- Kernel 3: tiny GEMM + bias + normalize --------------------------------
__global__ __launch_bounds__(256) void proto_kernel(
    const float* __restrict__ gsum, const float* __restrict__ gcnt,
    const float* __restrict__ W, const float* __restrict__ b,
    float* __restrict__ out)
{
    const int t = (int)(blockIdx.x * blockDim.x + threadIdx.x);
    const int c = t >> 6;
    const int e = t & 63;

    const float* srow = gsum + (c << 7);
    float acc = 0.0f;
#pragma unroll
    for (int k = 0; k < D_IN; ++k)
        acc = fmaf(srow[k], W[k * D_OUT + e], acc);

    const float cnt = gcnt[c];
    out[(c << 6) + e] = (acc + cnt * b[e]) / fmaxf(cnt, 1.0f);
}

extern "C" void kernel_launch(void* const* d_in, const int* in_sizes, int n_in,
                              void* d_out, int out_size, void* d_ws, size_t ws_size,
                              hipStream_t stream)
{
    const float* x      = (const float*)d_in[0];
    const int*   labels = (const int*)d_in[1];
    const float* W      = (const float*)d_in[2];
    const float* b      = (const float*)d_in[3];
    float*       out    = (float*)d_out;

    float* gsum = (float*)d_ws;                 // [64*128]
    float* gcnt = gsum + C_CLASSES * D_IN;      // [64]
    const int n = in_sizes[0] / D_IN;           // 1,000,000 (multiple of 64)

    hipMemsetAsync(d_ws, 0, (C_CLASSES * D_IN + C_CLASSES) * sizeof(float), stream);

    // 1024 blocks x 4 waves, 32 KB LDS each -> 4 blocks/CU, 16 waves/CU.
    seg_mm_kernel<<<1024, 256, 0, stream>>>(x, labels, gsum, n);

    count_kernel<<<256, 256, 0, stream>>>(labels, gcnt, n);

    proto_kernel<<<(C_CLASSES * D_OUT) / 256, 256, 0, stream>>>(gsum, gcnt, W, b, out);
}